// Round 5
// baseline (299.911 us; speedup 1.0000x reference)
//
#include <hip/hip_runtime.h>

#define BOHR_F 0.5291772105638411f
#define HA_D   27.211386024367243
#define A1_F   0.4289f
#define A2_F   4.4407f
#define S6_F   1.0f
#define S8_F   0.7875f
#define KCN_F  16.0f
#define WF_F   4.0f
#define EPS_F  1.1920929e-07f

// sort-path fixed point (22-bit fraction, 9-bit local atom id)
#define Q_SCALE 4194304.0f   // 2^22
#define Q_INV   (1.0f/4194304.0f)
#define Q_MAX   0x3FFFFFu
// atomic-fallback fixed point
#define CN_SCALE 8388608.0f  // 2^23
#define CN_INV   (1.0f/8388608.0f)

__device__ __forceinline__ float smooth_cutoff(float dr, float r_on, float r_cut) {
    float r_c = r_cut * r_cut;
    float r_o = r_on * r_on;
    float r   = dr * dr;
    float den = (r_c - r_o);
    float t   = r_c - r;
    float inner = (dr < r_cut)
        ? (t * t * (r_c + 2.0f * r - 3.0f * r_o)) / (den * den * den)
        : 0.0f;
    return (dr < r_on) ? 1.0f : inner;
}

__device__ __forceinline__ float edge_m(float dr, float rc) {
    if (!(dr > 0.0f)) return 0.0f;
    float count = 1.0f / (1.0f + expf(-KCN_F * (rc / dr - 1.0f)));
    return smooth_cutoff(dr, 20.0f, 25.0f) * count;
}

// ---------------- sort path ----------------
// Pass A: per-edge m -> packed {i&511 (9b) | q (22b)}; per-block bucket hist.
template<bool STASH>
__global__ __launch_bounds__(256)
void k_bin(const float* __restrict__ dr_vec,
           const int* __restrict__ idx_i, const int* __restrict__ idx_j,
           const int* __restrict__ numbers, const float* __restrict__ rcov,
           unsigned* __restrict__ packed, unsigned* __restrict__ ghist,
           float* __restrict__ dr_stash, int n_edges, int nb) {
    __shared__ unsigned hist[256];
    if ((int)threadIdx.x < nb) hist[threadIdx.x] = 0;
    __syncthreads();
    int stride = gridDim.x * blockDim.x;
    for (int e = blockIdx.x * blockDim.x + threadIdx.x; e < n_edges; e += stride) {
        float x = dr_vec[3 * e + 0];
        float y = dr_vec[3 * e + 1];
        float z = dr_vec[3 * e + 2];
        float dr = sqrtf(x * x + y * y + z * z) / BOHR_F;
        if (STASH) dr_stash[e] = dr;
        int i = idx_i[e];
        int j = idx_j[e];
        float rc = rcov[numbers[i]] + rcov[numbers[j]];
        float m = edge_m(dr, rc);
        unsigned q = (unsigned)(m * Q_SCALE + 0.5f);
        if (q > Q_MAX) q = Q_MAX;
        packed[e] = ((unsigned)(i & 511) << 22) | q;
        atomicAdd(&hist[i >> 9], 1u);
    }
    __syncthreads();
    if ((int)threadIdx.x < nb)
        ghist[(size_t)threadIdx.x * gridDim.x + blockIdx.x] = hist[threadIdx.x];
}

// Pass B: single-block exclusive prefix scan over ghist (bucket-major).
__global__ __launch_bounds__(1024)
void k_scan(unsigned* __restrict__ g, int ntot) {
    __shared__ unsigned part[1024];
    int t = threadIdx.x;
    int chunk = (ntot + 1023) / 1024;
    int lo = t * chunk;
    int hi = lo + chunk; if (hi > ntot) hi = ntot;
    unsigned s = 0;
    for (int k = lo; k < hi; ++k) s += g[k];
    part[t] = s;
    __syncthreads();
    for (int off = 1; off < 1024; off <<= 1) {
        unsigned v = (t >= off) ? part[t - off] : 0u;
        __syncthreads();
        part[t] += v;
        __syncthreads();
    }
    unsigned run = (t == 0) ? 0u : part[t - 1];
    for (int k = lo; k < hi; ++k) {
        unsigned v = g[k];
        g[k] = run;
        run += v;
    }
}

// Pass C: scatter packed values into bucket-sorted order (plain stores).
__global__ __launch_bounds__(256)
void k_scatter(const unsigned* __restrict__ packed,
               const int* __restrict__ idx_i,
               const unsigned* __restrict__ ghist,
               unsigned* __restrict__ pairs,
               int n_edges, int nb) {
    __shared__ unsigned ofs[256];
    if ((int)threadIdx.x < nb)
        ofs[threadIdx.x] = ghist[(size_t)threadIdx.x * gridDim.x + blockIdx.x];
    __syncthreads();
    int stride = gridDim.x * blockDim.x;
    for (int e = blockIdx.x * blockDim.x + threadIdx.x; e < n_edges; e += stride) {
        unsigned p = packed[e];
        int b = idx_i[e] >> 9;
        unsigned pos = atomicAdd(&ofs[b], 1u);  // LDS rank
        pairs[pos] = p;
    }
}

// Pass D: per-bucket LDS u32 reduce -> cn; fused weights -> atom records
// rec[a*8] = {w0..w4, r4r2[Z], unused, unused}
__global__ __launch_bounds__(256)
void k_reduce_weights(const unsigned* __restrict__ pairs,
                      const unsigned* __restrict__ ghist,
                      const int* __restrict__ numbers,
                      const float* __restrict__ ref_cn_table,
                      const float* __restrict__ r4r2,
                      float* __restrict__ rec,
                      int n_atoms, int n_edges, int nblk, int nb) {
    __shared__ unsigned hist[512];
    hist[threadIdx.x] = 0;
    hist[threadIdx.x + 256] = 0;
    __syncthreads();
    int b = blockIdx.x;
    unsigned start = ghist[(size_t)b * nblk];
    unsigned end = (b + 1 < nb) ? ghist[(size_t)(b + 1) * nblk] : (unsigned)n_edges;
    for (unsigned k = start + threadIdx.x; k < end; k += 256) {
        unsigned p = pairs[k];
        atomicAdd(&hist[p >> 22], p & Q_MAX);
    }
    __syncthreads();
    for (int l = threadIdx.x; l < 512; l += 256) {
        int a = (b << 9) + l;
        if (a < n_atoms) {
            float c = (float)hist[l] * Q_INV;
            int Z = numbers[a];
            float w[5];
            float s = 0.0f;
#pragma unroll
            for (int r = 0; r < 5; ++r) {
                float rcn = ref_cn_table[Z * 5 + r];
                float d = rcn - c;
                float wv = (rcn >= 0.0f) ? expf(-WF_F * d * d) : 0.0f;
                w[r] = wv;
                s += wv;
            }
            float den = s + EPS_F;
            float* rr = rec + (size_t)a * 8;
#pragma unroll
            for (int r = 0; r < 5; ++r) rr[r] = w[r] / den;
            rr[5] = r4r2[Z];
        }
    }
}

// ---------------- atomic fallback path ----------------
template<bool STASH>
__global__ __launch_bounds__(256)
void k_edges_cn_atomic(const float* __restrict__ dr_vec,
                       const int* __restrict__ idx_i,
                       const int* __restrict__ idx_j,
                       const int* __restrict__ numbers,
                       const float* __restrict__ rcov,
                       unsigned* __restrict__ cn_u32,
                       float* __restrict__ dr_stash,
                       int n_edges) {
    int e = blockIdx.x * blockDim.x + threadIdx.x;
    if (e >= n_edges) return;
    float x = dr_vec[3 * e + 0];
    float y = dr_vec[3 * e + 1];
    float z = dr_vec[3 * e + 2];
    float dr = sqrtf(x * x + y * y + z * z) / BOHR_F;
    if (STASH) dr_stash[e] = dr;
    int i = idx_i[e];
    int j = idx_j[e];
    float rc = rcov[numbers[i]] + rcov[numbers[j]];
    float m = edge_m(dr, rc);
    unsigned q = (unsigned)(m * CN_SCALE + 0.5f);
    if (q) atomicAdd(&cn_u32[i], q);
}

__global__ __launch_bounds__(256)
void k_atom_weights_rec(const unsigned* __restrict__ cn_u32,
                        const int* __restrict__ numbers,
                        const float* __restrict__ ref_cn_table,
                        const float* __restrict__ r4r2,
                        float* __restrict__ rec,
                        int n_atoms) {
    int tid = blockIdx.x * blockDim.x + threadIdx.x;
    int stride = gridDim.x * blockDim.x;
    for (int a = tid; a < n_atoms; a += stride) {
        float c = (float)cn_u32[a] * CN_INV;
        int Z = numbers[a];
        float w[5];
        float s = 0.0f;
#pragma unroll
        for (int r = 0; r < 5; ++r) {
            float rcn = ref_cn_table[Z * 5 + r];
            float d = rcn - c;
            float wv = (rcn >= 0.0f) ? expf(-WF_F * d * d) : 0.0f;
            w[r] = wv;
            s += wv;
        }
        float den = s + EPS_F;
        float* rr = rec + (size_t)a * 8;
#pragma unroll
        for (int r = 0; r < 5; ++r) rr[r] = w[r] / den;
        rr[5] = r4r2[Z];
    }
}

// ---------------- energy (shared) ----------------
template<bool STASH>
__global__ __launch_bounds__(256)
void k_energy(const float* __restrict__ dr_vec,
              const float* __restrict__ dr_stash,
              const int* __restrict__ idx_i,
              const int* __restrict__ idx_j,
              const int* __restrict__ numbers,
              const float* __restrict__ rec,     // [N,8]
              const float* __restrict__ ref_c6,  // [95,95,5,5]
              double* __restrict__ e_acc,
              int n_edges) {
    double local = 0.0;
    int nquad = (n_edges + 3) >> 2;
    int tid = blockIdx.x * blockDim.x + threadIdx.x;
    int stride = gridDim.x * blockDim.x;
    for (int qd = tid; qd < nquad; qd += stride) {
        int e0 = qd << 2;
        int ne = n_edges - e0;
        if (ne > 4) ne = 4;
        if (ne == 4) {
            int4 i4 = *reinterpret_cast<const int4*>(idx_i + e0);
            int4 j4 = *reinterpret_cast<const int4*>(idx_j + e0);
            int ia[4] = { i4.x, i4.y, i4.z, i4.w };
            int ja[4] = { j4.x, j4.y, j4.z, j4.w };
            float drq[4];
            if (STASH) {
                float4 d4 = *reinterpret_cast<const float4*>(dr_stash + e0);
                drq[0] = d4.x; drq[1] = d4.y; drq[2] = d4.z; drq[3] = d4.w;
            } else {
                float4 v0 = *reinterpret_cast<const float4*>(dr_vec + 3 * e0);
                float4 v1 = *reinterpret_cast<const float4*>(dr_vec + 3 * e0 + 4);
                float4 v2 = *reinterpret_cast<const float4*>(dr_vec + 3 * e0 + 8);
                drq[0] = sqrtf(v0.x*v0.x + v0.y*v0.y + v0.z*v0.z) / BOHR_F;
                drq[1] = sqrtf(v0.w*v0.w + v1.x*v1.x + v1.y*v1.y) / BOHR_F;
                drq[2] = sqrtf(v1.z*v1.z + v1.w*v1.w + v2.x*v2.x) / BOHR_F;
                drq[3] = sqrtf(v2.y*v2.y + v2.z*v2.z + v2.w*v2.w) / BOHR_F;
            }
            int Zi[4], Zj[4];
#pragma unroll
            for (int k = 0; k < 4; ++k) { Zi[k] = numbers[ia[k]]; Zj[k] = numbers[ja[k]]; }
            float4 ri0[4], ri1[4], rj0[4], rj1[4];
#pragma unroll
            for (int k = 0; k < 4; ++k) {
                const float4* pi = reinterpret_cast<const float4*>(rec + (size_t)ia[k] * 8);
                const float4* pj = reinterpret_cast<const float4*>(rec + (size_t)ja[k] * 8);
                ri0[k] = pi[0]; ri1[k] = pi[1];
                rj0[k] = pj[0]; rj1[k] = pj[1];
            }
#pragma unroll
            for (int k = 0; k < 4; ++k) {
                float wi[5] = { ri0[k].x, ri0[k].y, ri0[k].z, ri0[k].w, ri1[k].x };
                float wj[5] = { rj0[k].x, rj0[k].y, rj0[k].z, rj0[k].w, rj1[k].x };
                float qq = 3.0f * ri1[k].y * rj1[k].y;
                const float* c6t = ref_c6 + ((size_t)Zj[k] * 95 + (size_t)Zi[k]) * 25;
                float c6 = 0.0f;
#pragma unroll
                for (int a = 0; a < 5; ++a) {
#pragma unroll
                    for (int b = 0; b < 5; ++b) {
                        c6 += wj[a] * wi[b] * c6t[a * 5 + b];
                    }
                }
                float dr = drq[k];
                float rr = A1_F * sqrtf(qq) + A2_F;
                float dr2 = dr * dr;
                float dr6 = dr2 * dr2 * dr2;
                float dr8 = dr6 * dr2;
                float rr2 = rr * rr;
                float rr6 = rr2 * rr2 * rr2;
                float rr8 = rr6 * rr2;
                float damped = -c6 * (S6_F / (dr6 + rr6) + S8_F * qq / (dr8 + rr8));
                local += (double)(smooth_cutoff(dr, 55.0f, 60.0f) * damped * 0.5f);
            }
        } else {
            for (int k = 0; k < ne; ++k) {
                int e = e0 + k;
                float dr;
                if (STASH) dr = dr_stash[e];
                else {
                    float x = dr_vec[3*e], y = dr_vec[3*e+1], z = dr_vec[3*e+2];
                    dr = sqrtf(x*x + y*y + z*z) / BOHR_F;
                }
                int i = idx_i[e], j = idx_j[e];
                int zi = numbers[i], zj = numbers[j];
                const float* pi = rec + (size_t)i * 8;
                const float* pj = rec + (size_t)j * 8;
                float qq = 3.0f * pi[5] * pj[5];
                const float* c6t = ref_c6 + ((size_t)zj * 95 + (size_t)zi) * 25;
                float c6 = 0.0f;
                for (int a = 0; a < 5; ++a)
                    for (int bq = 0; bq < 5; ++bq)
                        c6 += pj[a] * pi[bq] * c6t[a * 5 + bq];
                float rr = A1_F * sqrtf(qq) + A2_F;
                float dr2 = dr * dr;
                float dr6 = dr2 * dr2 * dr2;
                float dr8 = dr6 * dr2;
                float rr2 = rr * rr;
                float rr6 = rr2 * rr2 * rr2;
                float rr8 = rr6 * rr2;
                float damped = -c6 * (S6_F / (dr6 + rr6) + S8_F * qq / (dr8 + rr8));
                local += (double)(smooth_cutoff(dr, 55.0f, 60.0f) * damped * 0.5f);
            }
        }
    }

    __shared__ double sdata[4];
    for (int off = 32; off > 0; off >>= 1)
        local += __shfl_down(local, off, 64);
    int lane = threadIdx.x & 63;
    int wid  = threadIdx.x >> 6;
    if (lane == 0) sdata[wid] = local;
    __syncthreads();
    if (threadIdx.x == 0) {
        double s = sdata[0] + sdata[1] + sdata[2] + sdata[3];
        atomicAdd(e_acc, s);
    }
}

__global__ void k_finalize(const double* __restrict__ e_acc,
                           float* __restrict__ out) {
    out[0] = (float)(e_acc[0] * HA_D);
}

static inline size_t a16(size_t x) { return (x + 15) & ~(size_t)15; }

extern "C" void kernel_launch(void* const* d_in, const int* in_sizes, int n_in,
                              void* d_out, int out_size, void* d_ws, size_t ws_size,
                              hipStream_t stream) {
    const float* dr_vec      = (const float*)d_in[0];
    const float* ref_cn_tab  = (const float*)d_in[1];
    const float* ref_c6_tab  = (const float*)d_in[2];
    const float* r4r2        = (const float*)d_in[3];
    const float* rcov        = (const float*)d_in[4];
    const int*   numbers     = (const int*)d_in[5];
    const int*   idx         = (const int*)d_in[6];

    int n_atoms = in_sizes[5];
    int n_edges = in_sizes[6] / 2;
    const int* idx_i = idx;
    const int* idx_j = idx + n_edges;

    const int BS = 256;
    const int NBLK = 256;                       // bin/scatter grid
    int nb = (n_atoms + 511) >> 9;              // buckets of 512 atoms

    char* ws = (char*)d_ws;
    double* e_acc = (double*)ws;

    // sort-path layout
    size_t off_rec    = 16;
    size_t off_packed = a16(off_rec + (size_t)n_atoms * 8 * 4);
    size_t off_pairs  = a16(off_packed + (size_t)n_edges * 4);
    size_t off_ghist  = a16(off_pairs + (size_t)n_edges * 4);
    size_t off_stash1 = a16(off_ghist + (size_t)nb * NBLK * 4);
    size_t need_sort  = off_stash1;
    size_t need_sort_stash = off_stash1 + (size_t)n_edges * 4;

    int nquad = (n_edges + 3) >> 2;
    int grid_q = (nquad + BS - 1) / BS;
    if (grid_q > 8192) grid_q = 8192;

    if (nb <= 256 && ws_size >= need_sort) {
        bool stash = (ws_size >= need_sort_stash);
        float*    rec    = (float*)(ws + off_rec);
        unsigned* packed = (unsigned*)(ws + off_packed);
        unsigned* pairs  = (unsigned*)(ws + off_pairs);
        unsigned* ghist  = (unsigned*)(ws + off_ghist);
        float* dr_stash  = stash ? (float*)(ws + off_stash1) : nullptr;

        hipMemsetAsync(d_ws, 0, 16, stream);   // e_acc only

        if (stash)
            k_bin<true><<<NBLK, BS, 0, stream>>>(dr_vec, idx_i, idx_j, numbers,
                rcov, packed, ghist, dr_stash, n_edges, nb);
        else
            k_bin<false><<<NBLK, BS, 0, stream>>>(dr_vec, idx_i, idx_j, numbers,
                rcov, packed, ghist, nullptr, n_edges, nb);

        k_scan<<<1, 1024, 0, stream>>>(ghist, nb * NBLK);

        k_scatter<<<NBLK, BS, 0, stream>>>(packed, idx_i, ghist, pairs,
                                           n_edges, nb);

        k_reduce_weights<<<nb, BS, 0, stream>>>(pairs, ghist, numbers,
            ref_cn_tab, r4r2, rec, n_atoms, n_edges, NBLK, nb);

        if (stash)
            k_energy<true><<<grid_q, BS, 0, stream>>>(dr_vec, dr_stash, idx_i,
                idx_j, numbers, rec, ref_c6_tab, e_acc, n_edges);
        else
            k_energy<false><<<grid_q, BS, 0, stream>>>(dr_vec, nullptr, idx_i,
                idx_j, numbers, rec, ref_c6_tab, e_acc, n_edges);
    } else {
        // atomic fallback: [e_acc][cn_u32 N][rec N*8][stash E]
        size_t off_cn   = 16;
        size_t off_recf = a16(off_cn + (size_t)n_atoms * 4);
        size_t off_st   = a16(off_recf + (size_t)n_atoms * 8 * 4);
        bool stash = (ws_size >= off_st + (size_t)n_edges * 4);

        unsigned* cn_u32 = (unsigned*)(ws + off_cn);
        float* rec       = (float*)(ws + off_recf);
        float* dr_stash  = stash ? (float*)(ws + off_st) : nullptr;

        hipMemsetAsync(d_ws, 0, off_recf, stream);   // e_acc + cn

        int grid_e = (n_edges + BS - 1) / BS;
        int grid_a = (n_atoms + BS - 1) / BS;
        if (grid_a > 2048) grid_a = 2048;

        if (stash)
            k_edges_cn_atomic<true><<<grid_e, BS, 0, stream>>>(dr_vec, idx_i,
                idx_j, numbers, rcov, cn_u32, dr_stash, n_edges);
        else
            k_edges_cn_atomic<false><<<grid_e, BS, 0, stream>>>(dr_vec, idx_i,
                idx_j, numbers, rcov, cn_u32, nullptr, n_edges);

        k_atom_weights_rec<<<grid_a, BS, 0, stream>>>(cn_u32, numbers,
            ref_cn_tab, r4r2, rec, n_atoms);

        if (stash)
            k_energy<true><<<grid_q, BS, 0, stream>>>(dr_vec, dr_stash, idx_i,
                idx_j, numbers, rec, ref_c6_tab, e_acc, n_edges);
        else
            k_energy<false><<<grid_q, BS, 0, stream>>>(dr_vec, nullptr, idx_i,
                idx_j, numbers, rec, ref_c6_tab, e_acc, n_edges);
    }

    k_finalize<<<1, 1, 0, stream>>>(e_acc, (float*)d_out);
}

// Round 6
// 256.541 us; speedup vs baseline: 1.1691x; 1.1691x over previous
//
#include <hip/hip_runtime.h>

#define BOHR_F 0.5291772105638411f
#define HA_D   27.211386024367243
#define A1_F   0.4289f
#define A2_F   4.4407f
#define S6_F   1.0f
#define S8_F   0.7875f
#define KCN_F  16.0f
#define WF_F   4.0f
#define EPS_F  1.1920929e-07f

// sort-path fixed point (22-bit fraction, 9-bit local atom id)
#define Q_SCALE 4194304.0f   // 2^22
#define Q_INV   (1.0f/4194304.0f)
#define Q_MAX   0x3FFFFFu
// atomic-fallback fixed point
#define CN_SCALE 8388608.0f  // 2^23
#define CN_INV   (1.0f/8388608.0f)

#define NELEM 95
#define C6PAD 28             // 25 -> 28 (7 x float4, 112B row, 16B aligned)

__device__ __forceinline__ float smooth_cutoff(float dr, float r_on, float r_cut) {
    float r_c = r_cut * r_cut;
    float r_o = r_on * r_on;
    float r   = dr * dr;
    float den = (r_c - r_o);
    float t   = r_c - r;
    float inner = (dr < r_cut)
        ? (t * t * (r_c + 2.0f * r - 3.0f * r_o)) / (den * den * den)
        : 0.0f;
    return (dr < r_on) ? 1.0f : inner;
}

__device__ __forceinline__ float edge_m(float dr, float rc) {
    if (!(dr > 0.0f)) return 0.0f;
    float count = 1.0f / (1.0f + expf(-KCN_F * (rc / dr - 1.0f)));
    return smooth_cutoff(dr, 20.0f, 25.0f) * count;
}

// ---------------- prep ----------------
// pad ref_c6 [95][95][25] -> [95*95][28] (tail zeros)
__global__ __launch_bounds__(256)
void k_prep_c6(const float* __restrict__ src, float* __restrict__ dst, int ntot) {
    int o = blockIdx.x * blockDim.x + threadIdx.x;
    if (o >= ntot) return;
    int p = o / C6PAD;
    int t = o - p * C6PAD;
    dst[o] = (t < 25) ? src[p * 25 + t] : 0.0f;
}

// rcovA[a] = rcov[numbers[a]]
__global__ __launch_bounds__(256)
void k_prep_rcov(const int* __restrict__ numbers, const float* __restrict__ rcov,
                 float* __restrict__ rcovA, int n_atoms) {
    int a = blockIdx.x * blockDim.x + threadIdx.x;
    if (a < n_atoms) rcovA[a] = rcov[numbers[a]];
}

// ---------------- sort path ----------------
// Pass A: per-edge m -> packed {i&511 (9b) | q (22b)}; per-block bucket hist.
template<bool STASH>
__global__ __launch_bounds__(1024)
void k_bin(const float* __restrict__ dr_vec,
           const int* __restrict__ idx_i, const int* __restrict__ idx_j,
           const float* __restrict__ rcovA,
           unsigned* __restrict__ packed, unsigned* __restrict__ ghist,
           float* __restrict__ dr_stash, int n_edges, int nb) {
    __shared__ unsigned hist[256];
    if (threadIdx.x < 256) hist[threadIdx.x] = 0;
    __syncthreads();
    int nquad = (n_edges + 3) >> 2;
    int stride = gridDim.x * blockDim.x;
    for (int qd = blockIdx.x * blockDim.x + threadIdx.x; qd < nquad; qd += stride) {
        int e0 = qd << 2;
        int ne = n_edges - e0; if (ne > 4) ne = 4;
        if (ne == 4) {
            float4 v0 = *reinterpret_cast<const float4*>(dr_vec + 3 * e0);
            float4 v1 = *reinterpret_cast<const float4*>(dr_vec + 3 * e0 + 4);
            float4 v2 = *reinterpret_cast<const float4*>(dr_vec + 3 * e0 + 8);
            float drq[4];
            drq[0] = sqrtf(v0.x*v0.x + v0.y*v0.y + v0.z*v0.z) / BOHR_F;
            drq[1] = sqrtf(v0.w*v0.w + v1.x*v1.x + v1.y*v1.y) / BOHR_F;
            drq[2] = sqrtf(v1.z*v1.z + v1.w*v1.w + v2.x*v2.x) / BOHR_F;
            drq[3] = sqrtf(v2.y*v2.y + v2.z*v2.z + v2.w*v2.w) / BOHR_F;
            int4 i4 = *reinterpret_cast<const int4*>(idx_i + e0);
            int4 j4 = *reinterpret_cast<const int4*>(idx_j + e0);
            int ia[4] = { i4.x, i4.y, i4.z, i4.w };
            int ja[4] = { j4.x, j4.y, j4.z, j4.w };
            float rcq[4];
#pragma unroll
            for (int k = 0; k < 4; ++k) rcq[k] = rcovA[ia[k]] + rcovA[ja[k]];
            unsigned pk[4];
#pragma unroll
            for (int k = 0; k < 4; ++k) {
                float m = edge_m(drq[k], rcq[k]);
                unsigned q = (unsigned)(m * Q_SCALE + 0.5f);
                if (q > Q_MAX) q = Q_MAX;
                pk[k] = ((unsigned)(ia[k] & 511) << 22) | q;
                atomicAdd(&hist[ia[k] >> 9], 1u);
            }
            *reinterpret_cast<uint4*>(packed + e0) = make_uint4(pk[0], pk[1], pk[2], pk[3]);
            if (STASH)
                *reinterpret_cast<float4*>(dr_stash + e0) =
                    make_float4(drq[0], drq[1], drq[2], drq[3]);
        } else {
            for (int k = 0; k < ne; ++k) {
                int e = e0 + k;
                float x = dr_vec[3*e], y = dr_vec[3*e+1], z = dr_vec[3*e+2];
                float dr = sqrtf(x*x + y*y + z*z) / BOHR_F;
                if (STASH) dr_stash[e] = dr;
                int i = idx_i[e], j = idx_j[e];
                float m = edge_m(dr, rcovA[i] + rcovA[j]);
                unsigned q = (unsigned)(m * Q_SCALE + 0.5f);
                if (q > Q_MAX) q = Q_MAX;
                packed[e] = ((unsigned)(i & 511) << 22) | q;
                atomicAdd(&hist[i >> 9], 1u);
            }
        }
    }
    __syncthreads();
    if ((int)threadIdx.x < nb)
        ghist[(size_t)threadIdx.x * gridDim.x + blockIdx.x] = hist[threadIdx.x];
}

// Pass B: single-block exclusive prefix scan over ghist (bucket-major).
__global__ __launch_bounds__(1024)
void k_scan(unsigned* __restrict__ g, int ntot) {
    __shared__ unsigned part[1024];
    int t = threadIdx.x;
    int chunk = (ntot + 1023) / 1024;
    int lo = t * chunk;
    int hi = lo + chunk; if (hi > ntot) hi = ntot;
    unsigned s = 0;
    for (int k = lo; k < hi; ++k) s += g[k];
    part[t] = s;
    __syncthreads();
    for (int off = 1; off < 1024; off <<= 1) {
        unsigned v = (t >= off) ? part[t - off] : 0u;
        __syncthreads();
        part[t] += v;
        __syncthreads();
    }
    unsigned run = (t == 0) ? 0u : part[t - 1];
    for (int k = lo; k < hi; ++k) {
        unsigned v = g[k];
        g[k] = run;
        run += v;
    }
}

// Pass C: scatter packed values into bucket-sorted order (plain stores).
__global__ __launch_bounds__(1024)
void k_scatter(const unsigned* __restrict__ packed,
               const int* __restrict__ idx_i,
               const unsigned* __restrict__ ghist,
               unsigned* __restrict__ pairs,
               int n_edges, int nb) {
    __shared__ unsigned ofs[256];
    if ((int)threadIdx.x < nb)
        ofs[threadIdx.x] = ghist[(size_t)threadIdx.x * gridDim.x + blockIdx.x];
    __syncthreads();
    int nquad = (n_edges + 3) >> 2;
    int stride = gridDim.x * blockDim.x;
    for (int qd = blockIdx.x * blockDim.x + threadIdx.x; qd < nquad; qd += stride) {
        int e0 = qd << 2;
        int ne = n_edges - e0; if (ne > 4) ne = 4;
        if (ne == 4) {
            uint4 p4 = *reinterpret_cast<const uint4*>(packed + e0);
            int4  i4 = *reinterpret_cast<const int4*>(idx_i + e0);
            unsigned pk[4] = { p4.x, p4.y, p4.z, p4.w };
            int ia[4] = { i4.x, i4.y, i4.z, i4.w };
#pragma unroll
            for (int k = 0; k < 4; ++k) {
                unsigned pos = atomicAdd(&ofs[ia[k] >> 9], 1u);
                pairs[pos] = pk[k];
            }
        } else {
            for (int k = 0; k < ne; ++k) {
                int e = e0 + k;
                unsigned pos = atomicAdd(&ofs[idx_i[e] >> 9], 1u);
                pairs[pos] = packed[e];
            }
        }
    }
}

// Pass D: per-bucket LDS u32 reduce -> cn; fused weights -> atom records
// rec[a*8] = {w0..w4, r4r2[Z], Z_bits, 0}
__global__ __launch_bounds__(512)
void k_reduce_weights(const unsigned* __restrict__ pairs,
                      const unsigned* __restrict__ ghist,
                      const int* __restrict__ numbers,
                      const float* __restrict__ ref_cn_table,
                      const float* __restrict__ r4r2,
                      float* __restrict__ rec,
                      int n_atoms, int n_edges, int nblk, int nb) {
    __shared__ unsigned hist[512];
    hist[threadIdx.x] = 0;
    __syncthreads();
    int b = blockIdx.x;
    unsigned start = ghist[(size_t)b * nblk];
    unsigned end = (b + 1 < nb) ? ghist[(size_t)(b + 1) * nblk] : (unsigned)n_edges;
    for (unsigned k = start + threadIdx.x; k < end; k += 512) {
        unsigned p = pairs[k];
        atomicAdd(&hist[p >> 22], p & Q_MAX);
    }
    __syncthreads();
    int a = (b << 9) + threadIdx.x;
    if (a < n_atoms) {
        float c = (float)hist[threadIdx.x] * Q_INV;
        int Z = numbers[a];
        float w[5];
        float s = 0.0f;
#pragma unroll
        for (int r = 0; r < 5; ++r) {
            float rcn = ref_cn_table[Z * 5 + r];
            float d = rcn - c;
            float wv = (rcn >= 0.0f) ? expf(-WF_F * d * d) : 0.0f;
            w[r] = wv;
            s += wv;
        }
        float den = s + EPS_F;
        float* rr = rec + (size_t)a * 8;
#pragma unroll
        for (int r = 0; r < 5; ++r) rr[r] = w[r] / den;
        rr[5] = r4r2[Z];
        rr[6] = __int_as_float(Z);
        rr[7] = 0.0f;
    }
}

// ---------------- atomic fallback path ----------------
template<bool STASH>
__global__ __launch_bounds__(256)
void k_edges_cn_atomic(const float* __restrict__ dr_vec,
                       const int* __restrict__ idx_i,
                       const int* __restrict__ idx_j,
                       const float* __restrict__ rcovA,
                       unsigned* __restrict__ cn_u32,
                       float* __restrict__ dr_stash,
                       int n_edges) {
    int e = blockIdx.x * blockDim.x + threadIdx.x;
    if (e >= n_edges) return;
    float x = dr_vec[3 * e + 0];
    float y = dr_vec[3 * e + 1];
    float z = dr_vec[3 * e + 2];
    float dr = sqrtf(x * x + y * y + z * z) / BOHR_F;
    if (STASH) dr_stash[e] = dr;
    int i = idx_i[e];
    int j = idx_j[e];
    float m = edge_m(dr, rcovA[i] + rcovA[j]);
    unsigned q = (unsigned)(m * CN_SCALE + 0.5f);
    if (q) atomicAdd(&cn_u32[i], q);
}

__global__ __launch_bounds__(256)
void k_atom_weights_rec(const unsigned* __restrict__ cn_u32,
                        const int* __restrict__ numbers,
                        const float* __restrict__ ref_cn_table,
                        const float* __restrict__ r4r2,
                        float* __restrict__ rec,
                        int n_atoms) {
    int a = blockIdx.x * blockDim.x + threadIdx.x;
    if (a >= n_atoms) return;
    float c = (float)cn_u32[a] * CN_INV;
    int Z = numbers[a];
    float w[5];
    float s = 0.0f;
#pragma unroll
    for (int r = 0; r < 5; ++r) {
        float rcn = ref_cn_table[Z * 5 + r];
        float d = rcn - c;
        float wv = (rcn >= 0.0f) ? expf(-WF_F * d * d) : 0.0f;
        w[r] = wv;
        s += wv;
    }
    float den = s + EPS_F;
    float* rr = rec + (size_t)a * 8;
#pragma unroll
    for (int r = 0; r < 5; ++r) rr[r] = w[r] / den;
    rr[5] = r4r2[Z];
    rr[6] = __int_as_float(Z);
    rr[7] = 0.0f;
}

// ---------------- energy (shared) ----------------
template<bool STASH>
__global__ __launch_bounds__(256)
void k_energy(const float* __restrict__ dr_vec,
              const float* __restrict__ dr_stash,
              const int* __restrict__ idx_i,
              const int* __restrict__ idx_j,
              const float* __restrict__ rec,     // [N,8] {w0..4, qqh, Zbits, 0}
              const float* __restrict__ c6pad,   // [95*95][28]
              double* __restrict__ e_acc,
              int n_edges) {
    double local = 0.0;
    int nquad = (n_edges + 3) >> 2;
    int tid = blockIdx.x * blockDim.x + threadIdx.x;
    int stride = gridDim.x * blockDim.x;
    for (int qd = tid; qd < nquad; qd += stride) {
        int e0 = qd << 2;
        int ne = n_edges - e0;
        if (ne > 4) ne = 4;
        if (ne == 4) {
            int4 i4 = *reinterpret_cast<const int4*>(idx_i + e0);
            int4 j4 = *reinterpret_cast<const int4*>(idx_j + e0);
            int ia[4] = { i4.x, i4.y, i4.z, i4.w };
            int ja[4] = { j4.x, j4.y, j4.z, j4.w };
            float drq[4];
            if (STASH) {
                float4 d4 = *reinterpret_cast<const float4*>(dr_stash + e0);
                drq[0] = d4.x; drq[1] = d4.y; drq[2] = d4.z; drq[3] = d4.w;
            } else {
                float4 v0 = *reinterpret_cast<const float4*>(dr_vec + 3 * e0);
                float4 v1 = *reinterpret_cast<const float4*>(dr_vec + 3 * e0 + 4);
                float4 v2 = *reinterpret_cast<const float4*>(dr_vec + 3 * e0 + 8);
                drq[0] = sqrtf(v0.x*v0.x + v0.y*v0.y + v0.z*v0.z) / BOHR_F;
                drq[1] = sqrtf(v0.w*v0.w + v1.x*v1.x + v1.y*v1.y) / BOHR_F;
                drq[2] = sqrtf(v1.z*v1.z + v1.w*v1.w + v2.x*v2.x) / BOHR_F;
                drq[3] = sqrtf(v2.y*v2.y + v2.z*v2.z + v2.w*v2.w) / BOHR_F;
            }
            float4 ri0[4], ri1[4], rj0[4], rj1[4];
#pragma unroll
            for (int k = 0; k < 4; ++k) {
                const float4* pi = reinterpret_cast<const float4*>(rec + (size_t)ia[k] * 8);
                const float4* pj = reinterpret_cast<const float4*>(rec + (size_t)ja[k] * 8);
                ri0[k] = pi[0]; ri1[k] = pi[1];
                rj0[k] = pj[0]; rj1[k] = pj[1];
            }
#pragma unroll
            for (int k = 0; k < 4; ++k) {
                float wi[5] = { ri0[k].x, ri0[k].y, ri0[k].z, ri0[k].w, ri1[k].x };
                float wj[5] = { rj0[k].x, rj0[k].y, rj0[k].z, rj0[k].w, rj1[k].x };
                float qq = 3.0f * ri1[k].y * rj1[k].y;
                int Zi = __float_as_int(ri1[k].z);
                int Zj = __float_as_int(rj1[k].z);
                const float4* ctv = reinterpret_cast<const float4*>(
                    c6pad + ((size_t)Zj * NELEM + (size_t)Zi) * C6PAD);
                float ct[28];
#pragma unroll
                for (int v = 0; v < 7; ++v) {
                    float4 c4 = ctv[v];
                    ct[4*v+0] = c4.x; ct[4*v+1] = c4.y;
                    ct[4*v+2] = c4.z; ct[4*v+3] = c4.w;
                }
                float c6 = 0.0f;
#pragma unroll
                for (int a = 0; a < 5; ++a) {
#pragma unroll
                    for (int b = 0; b < 5; ++b) {
                        c6 += wj[a] * wi[b] * ct[a * 5 + b];
                    }
                }
                float dr = drq[k];
                float rr = A1_F * sqrtf(qq) + A2_F;
                float dr2 = dr * dr;
                float dr6 = dr2 * dr2 * dr2;
                float dr8 = dr6 * dr2;
                float rr2 = rr * rr;
                float rr6 = rr2 * rr2 * rr2;
                float rr8 = rr6 * rr2;
                float damped = -c6 * (S6_F / (dr6 + rr6) + S8_F * qq / (dr8 + rr8));
                local += (double)(smooth_cutoff(dr, 55.0f, 60.0f) * damped * 0.5f);
            }
        } else {
            for (int k = 0; k < ne; ++k) {
                int e = e0 + k;
                float dr;
                if (STASH) dr = dr_stash[e];
                else {
                    float x = dr_vec[3*e], y = dr_vec[3*e+1], z = dr_vec[3*e+2];
                    dr = sqrtf(x*x + y*y + z*z) / BOHR_F;
                }
                int i = idx_i[e], j = idx_j[e];
                const float* pi = rec + (size_t)i * 8;
                const float* pj = rec + (size_t)j * 8;
                int zi = __float_as_int(pi[6]);
                int zj = __float_as_int(pj[6]);
                float qq = 3.0f * pi[5] * pj[5];
                const float* c6t = c6pad + ((size_t)zj * NELEM + (size_t)zi) * C6PAD;
                float c6 = 0.0f;
                for (int a = 0; a < 5; ++a)
                    for (int bq = 0; bq < 5; ++bq)
                        c6 += pj[a] * pi[bq] * c6t[a * 5 + bq];
                float rr = A1_F * sqrtf(qq) + A2_F;
                float dr2 = dr * dr;
                float dr6 = dr2 * dr2 * dr2;
                float dr8 = dr6 * dr2;
                float rr2 = rr * rr;
                float rr6 = rr2 * rr2 * rr2;
                float rr8 = rr6 * rr2;
                float damped = -c6 * (S6_F / (dr6 + rr6) + S8_F * qq / (dr8 + rr8));
                local += (double)(smooth_cutoff(dr, 55.0f, 60.0f) * damped * 0.5f);
            }
        }
    }

    __shared__ double sdata[4];
    for (int off = 32; off > 0; off >>= 1)
        local += __shfl_down(local, off, 64);
    int lane = threadIdx.x & 63;
    int wid  = threadIdx.x >> 6;
    if (lane == 0) sdata[wid] = local;
    __syncthreads();
    if (threadIdx.x == 0) {
        double s = sdata[0] + sdata[1] + sdata[2] + sdata[3];
        atomicAdd(e_acc, s);
    }
}

__global__ void k_finalize(const double* __restrict__ e_acc,
                           float* __restrict__ out) {
    out[0] = (float)(e_acc[0] * HA_D);
}

static inline size_t a16(size_t x) { return (x + 15) & ~(size_t)15; }

extern "C" void kernel_launch(void* const* d_in, const int* in_sizes, int n_in,
                              void* d_out, int out_size, void* d_ws, size_t ws_size,
                              hipStream_t stream) {
    const float* dr_vec      = (const float*)d_in[0];
    const float* ref_cn_tab  = (const float*)d_in[1];
    const float* ref_c6_tab  = (const float*)d_in[2];
    const float* r4r2        = (const float*)d_in[3];
    const float* rcov        = (const float*)d_in[4];
    const int*   numbers     = (const int*)d_in[5];
    const int*   idx         = (const int*)d_in[6];

    int n_atoms = in_sizes[5];
    int n_edges = in_sizes[6] / 2;
    const int* idx_i = idx;
    const int* idx_j = idx + n_edges;

    const int BS   = 256;
    const int BSW  = 1024;     // bin/scatter block size (16 waves/CU)
    const int NBLK = 256;      // bin/scatter grid (1 block/CU)
    int nb = (n_atoms + 511) >> 9;

    int c6tot = NELEM * NELEM * C6PAD;

    char* ws = (char*)d_ws;
    double* e_acc = (double*)ws;

    // common prefix: [e_acc 16][rec 8N][c6pad][rcovA N]
    size_t off_rec   = 16;
    size_t off_c6p   = a16(off_rec + (size_t)n_atoms * 8 * 4);
    size_t off_rcA   = a16(off_c6p + (size_t)c6tot * 4);
    size_t off_var   = a16(off_rcA + (size_t)n_atoms * 4);

    // sort path: [packed E][pairs E][ghist nb*NBLK][stash E]
    size_t off_packed = off_var;
    size_t off_pairs  = a16(off_packed + (size_t)n_edges * 4);
    size_t off_ghist  = a16(off_pairs + (size_t)n_edges * 4);
    size_t off_stash  = a16(off_ghist + (size_t)nb * NBLK * 4);
    size_t need_sort       = off_stash;
    size_t need_sort_stash = off_stash + (size_t)n_edges * 4;

    // atomic path: [cn N][stash E]
    size_t off_cn   = off_var;
    size_t off_st_a = a16(off_cn + (size_t)n_atoms * 4);
    size_t need_atomic_stash = off_st_a + (size_t)n_edges * 4;

    int nquad  = (n_edges + 3) >> 2;
    int grid_q = (nquad + BS - 1) / BS;
    if (grid_q > 8192) grid_q = 8192;
    int grid_c6 = (c6tot + BS - 1) / BS;
    int grid_a  = (n_atoms + BS - 1) / BS;

    float* rec   = (float*)(ws + off_rec);
    float* c6pad = (float*)(ws + off_c6p);
    float* rcovA = (float*)(ws + off_rcA);

    // prep (both paths)
    k_prep_c6<<<grid_c6, BS, 0, stream>>>(ref_c6_tab, c6pad, c6tot);
    k_prep_rcov<<<grid_a, BS, 0, stream>>>(numbers, rcov, rcovA, n_atoms);

    if (nb <= 256 && ws_size >= need_sort) {
        bool stash = (ws_size >= need_sort_stash);
        unsigned* packed = (unsigned*)(ws + off_packed);
        unsigned* pairs  = (unsigned*)(ws + off_pairs);
        unsigned* ghist  = (unsigned*)(ws + off_ghist);
        float* dr_stash  = stash ? (float*)(ws + off_stash) : nullptr;

        hipMemsetAsync(d_ws, 0, 16, stream);   // e_acc only

        if (stash)
            k_bin<true><<<NBLK, BSW, 0, stream>>>(dr_vec, idx_i, idx_j, rcovA,
                packed, ghist, dr_stash, n_edges, nb);
        else
            k_bin<false><<<NBLK, BSW, 0, stream>>>(dr_vec, idx_i, idx_j, rcovA,
                packed, ghist, nullptr, n_edges, nb);

        k_scan<<<1, 1024, 0, stream>>>(ghist, nb * NBLK);

        k_scatter<<<NBLK, BSW, 0, stream>>>(packed, idx_i, ghist, pairs,
                                            n_edges, nb);

        k_reduce_weights<<<nb, 512, 0, stream>>>(pairs, ghist, numbers,
            ref_cn_tab, r4r2, rec, n_atoms, n_edges, NBLK, nb);

        if (stash)
            k_energy<true><<<grid_q, BS, 0, stream>>>(dr_vec, dr_stash, idx_i,
                idx_j, rec, c6pad, e_acc, n_edges);
        else
            k_energy<false><<<grid_q, BS, 0, stream>>>(dr_vec, nullptr, idx_i,
                idx_j, rec, c6pad, e_acc, n_edges);
    } else {
        bool stash = (ws_size >= need_atomic_stash);
        unsigned* cn_u32 = (unsigned*)(ws + off_cn);
        float* dr_stash  = stash ? (float*)(ws + off_st_a) : nullptr;

        // zero e_acc + rec/c6pad-prefix not needed; zero e_acc and cn
        hipMemsetAsync(d_ws, 0, 16, stream);
        hipMemsetAsync(cn_u32, 0, (size_t)n_atoms * 4, stream);

        int grid_e = (n_edges + BS - 1) / BS;

        if (stash)
            k_edges_cn_atomic<true><<<grid_e, BS, 0, stream>>>(dr_vec, idx_i,
                idx_j, rcovA, cn_u32, dr_stash, n_edges);
        else
            k_edges_cn_atomic<false><<<grid_e, BS, 0, stream>>>(dr_vec, idx_i,
                idx_j, rcovA, cn_u32, nullptr, n_edges);

        k_atom_weights_rec<<<grid_a, BS, 0, stream>>>(cn_u32, numbers,
            ref_cn_tab, r4r2, rec, n_atoms);

        if (stash)
            k_energy<true><<<grid_q, BS, 0, stream>>>(dr_vec, dr_stash, idx_i,
                idx_j, rec, c6pad, e_acc, n_edges);
        else
            k_energy<false><<<grid_q, BS, 0, stream>>>(dr_vec, nullptr, idx_i,
                idx_j, rec, c6pad, e_acc, n_edges);
    }

    k_finalize<<<1, 1, 0, stream>>>(e_acc, (float*)d_out);
}

// Round 7
// 174.826 us; speedup vs baseline: 1.7155x; 1.4674x over previous
//
#include <hip/hip_runtime.h>
#include <hip/hip_fp16.h>

#define BOHR_F 0.5291772105638411f
#define HA_D   27.211386024367243
#define A1_F   0.4289f
#define A2_F   4.4407f
#define S6_F   1.0f
#define S8_F   0.7875f
#define KCN_F  16.0f
#define WF_F   4.0f
#define EPS_F  1.1920929e-07f

// sort-path fixed point (22-bit fraction, 9-bit local atom id)
#define Q_SCALE 4194304.0f   // 2^22
#define Q_INV   (1.0f/4194304.0f)
#define Q_MAX   0x3FFFFFu
// atomic-fallback fixed point
#define CN_SCALE 8388608.0f  // 2^23
#define CN_INV   (1.0f/8388608.0f)

#define NELEM  95
#define C6PADH 32            // 25 halfs -> 32 (64B row = 1 cache line)
#define NBLK   512           // bin/scatter grid
#define BSW    512           // bin/scatter block

__device__ __forceinline__ float smooth_cutoff(float dr, float r_on, float r_cut) {
    float r_c = r_cut * r_cut;
    float r_o = r_on * r_on;
    float r   = dr * dr;
    float den = (r_c - r_o);
    float t   = r_c - r;
    float inner = (dr < r_cut)
        ? (t * t * (r_c + 2.0f * r - 3.0f * r_o)) / (den * den * den)
        : 0.0f;
    return (dr < r_on) ? 1.0f : inner;
}

__device__ __forceinline__ float edge_m(float dr, float rc) {
    if (!(dr > 0.0f)) return 0.0f;
    float count = 1.0f / (1.0f + expf(-KCN_F * (rc / dr - 1.0f)));
    return smooth_cutoff(dr, 20.0f, 25.0f) * count;
}

__device__ __forceinline__ void u2f2(unsigned u, float& a, float& b) {
    __half2 h = __builtin_bit_cast(__half2, u);
    float2 f = __half22float2(h);
    a = f.x; b = f.y;
}

// ---------------- prep ----------------
// pad+convert ref_c6 [95][95][25] f32 -> [95*95][32] f16
__global__ __launch_bounds__(256)
void k_prep_c6(const float* __restrict__ src, __half* __restrict__ dst, int ntot) {
    int o = blockIdx.x * blockDim.x + threadIdx.x;
    if (o >= ntot) return;
    int p = o >> 5;
    int t = o & 31;
    dst[o] = __float2half((t < 25) ? src[p * 25 + t] : 0.0f);
}

// rcovA[a] = rcov[numbers[a]]
__global__ __launch_bounds__(256)
void k_prep_rcov(const int* __restrict__ numbers, const float* __restrict__ rcov,
                 float* __restrict__ rcovA, int n_atoms) {
    int a = blockIdx.x * blockDim.x + threadIdx.x;
    if (a < n_atoms) rcovA[a] = rcov[numbers[a]];
}

// ---------------- sort path ----------------
// Pass A: per-edge m -> packed {i&511 (9b) | q (22b)}; per-block bucket hist.
template<bool STASH>
__global__ __launch_bounds__(BSW, 4)
void k_bin(const float* __restrict__ dr_vec,
           const int* __restrict__ idx_i, const int* __restrict__ idx_j,
           const float* __restrict__ rcovA,
           unsigned* __restrict__ packed, unsigned* __restrict__ ghist,
           float* __restrict__ dr_stash, int n_edges, int nb) {
    __shared__ unsigned hist[256];
    if (threadIdx.x < 256) hist[threadIdx.x] = 0;
    __syncthreads();
    int nquad = (n_edges + 3) >> 2;
    int stride = gridDim.x * blockDim.x;
    for (int qd = blockIdx.x * blockDim.x + threadIdx.x; qd < nquad; qd += stride) {
        int e0 = qd << 2;
        int ne = n_edges - e0; if (ne > 4) ne = 4;
        if (ne == 4) {
            float4 v0 = *reinterpret_cast<const float4*>(dr_vec + 3 * e0);
            float4 v1 = *reinterpret_cast<const float4*>(dr_vec + 3 * e0 + 4);
            float4 v2 = *reinterpret_cast<const float4*>(dr_vec + 3 * e0 + 8);
            float drq[4];
            drq[0] = sqrtf(v0.x*v0.x + v0.y*v0.y + v0.z*v0.z) / BOHR_F;
            drq[1] = sqrtf(v0.w*v0.w + v1.x*v1.x + v1.y*v1.y) / BOHR_F;
            drq[2] = sqrtf(v1.z*v1.z + v1.w*v1.w + v2.x*v2.x) / BOHR_F;
            drq[3] = sqrtf(v2.y*v2.y + v2.z*v2.z + v2.w*v2.w) / BOHR_F;
            int4 i4 = *reinterpret_cast<const int4*>(idx_i + e0);
            int4 j4 = *reinterpret_cast<const int4*>(idx_j + e0);
            int ia[4] = { i4.x, i4.y, i4.z, i4.w };
            int ja[4] = { j4.x, j4.y, j4.z, j4.w };
            float rcq[4];
#pragma unroll
            for (int k = 0; k < 4; ++k) rcq[k] = rcovA[ia[k]] + rcovA[ja[k]];
            unsigned pk[4];
#pragma unroll
            for (int k = 0; k < 4; ++k) {
                float m = edge_m(drq[k], rcq[k]);
                unsigned q = (unsigned)(m * Q_SCALE + 0.5f);
                if (q > Q_MAX) q = Q_MAX;
                pk[k] = ((unsigned)(ia[k] & 511) << 22) | q;
                atomicAdd(&hist[ia[k] >> 9], 1u);
            }
            *reinterpret_cast<uint4*>(packed + e0) = make_uint4(pk[0], pk[1], pk[2], pk[3]);
            if (STASH)
                *reinterpret_cast<float4*>(dr_stash + e0) =
                    make_float4(drq[0], drq[1], drq[2], drq[3]);
        } else {
            for (int k = 0; k < ne; ++k) {
                int e = e0 + k;
                float x = dr_vec[3*e], y = dr_vec[3*e+1], z = dr_vec[3*e+2];
                float dr = sqrtf(x*x + y*y + z*z) / BOHR_F;
                if (STASH) dr_stash[e] = dr;
                int i = idx_i[e], j = idx_j[e];
                float m = edge_m(dr, rcovA[i] + rcovA[j]);
                unsigned q = (unsigned)(m * Q_SCALE + 0.5f);
                if (q > Q_MAX) q = Q_MAX;
                packed[e] = ((unsigned)(i & 511) << 22) | q;
                atomicAdd(&hist[i >> 9], 1u);
            }
        }
    }
    __syncthreads();
    if ((int)threadIdx.x < nb)
        ghist[(size_t)threadIdx.x * gridDim.x + blockIdx.x] = hist[threadIdx.x];
}

// Pass B1: per-bucket exclusive scan across NBLK block-counts (in place);
// write bucket total.
__global__ __launch_bounds__(NBLK)
void k_scan_bucket(unsigned* __restrict__ ghist, unsigned* __restrict__ totals) {
    __shared__ unsigned s[NBLK];
    int b = blockIdx.x;
    int t = threadIdx.x;
    unsigned v = ghist[(size_t)b * NBLK + t];
    s[t] = v;
    __syncthreads();
    for (int off = 1; off < NBLK; off <<= 1) {
        unsigned x = (t >= off) ? s[t - off] : 0u;
        __syncthreads();
        s[t] += x;
        __syncthreads();
    }
    ghist[(size_t)b * NBLK + t] = s[t] - v;   // exclusive
    if (t == NBLK - 1) totals[b] = s[t];
}

// Pass B2: exclusive scan over bucket totals -> base[nb+1].
__global__ __launch_bounds__(256)
void k_scan_base(const unsigned* __restrict__ totals,
                 unsigned* __restrict__ base, int nb) {
    __shared__ unsigned s[256];
    int t = threadIdx.x;
    unsigned v = (t < nb) ? totals[t] : 0u;
    s[t] = v;
    __syncthreads();
    for (int off = 1; off < 256; off <<= 1) {
        unsigned x = (t >= off) ? s[t - off] : 0u;
        __syncthreads();
        s[t] += x;
        __syncthreads();
    }
    if (t < nb) base[t] = s[t] - v;
    if (t == 255) base[nb] = s[t];
}

// Pass C: scatter packed values into bucket-sorted order (plain stores).
__global__ __launch_bounds__(BSW, 4)
void k_scatter(const unsigned* __restrict__ packed,
               const int* __restrict__ idx_i,
               const unsigned* __restrict__ ghist,
               const unsigned* __restrict__ base,
               unsigned* __restrict__ pairs,
               int n_edges, int nb) {
    __shared__ unsigned ofs[256];
    if ((int)threadIdx.x < nb)
        ofs[threadIdx.x] = base[threadIdx.x]
                         + ghist[(size_t)threadIdx.x * gridDim.x + blockIdx.x];
    __syncthreads();
    int nquad = (n_edges + 3) >> 2;
    int stride = gridDim.x * blockDim.x;
    for (int qd = blockIdx.x * blockDim.x + threadIdx.x; qd < nquad; qd += stride) {
        int e0 = qd << 2;
        int ne = n_edges - e0; if (ne > 4) ne = 4;
        if (ne == 4) {
            uint4 p4 = *reinterpret_cast<const uint4*>(packed + e0);
            int4  i4 = *reinterpret_cast<const int4*>(idx_i + e0);
            unsigned pk[4] = { p4.x, p4.y, p4.z, p4.w };
            int ia[4] = { i4.x, i4.y, i4.z, i4.w };
#pragma unroll
            for (int k = 0; k < 4; ++k) {
                unsigned pos = atomicAdd(&ofs[ia[k] >> 9], 1u);
                pairs[pos] = pk[k];
            }
        } else {
            for (int k = 0; k < ne; ++k) {
                int e = e0 + k;
                unsigned pos = atomicAdd(&ofs[idx_i[e] >> 9], 1u);
                pairs[pos] = packed[e];
            }
        }
    }
}

// Pass D: per-bucket LDS u32 reduce -> cn; fused weights -> half atom records
// rec[a*8] = {w0..w4, r4r2[Z], (half)Z, 0}
__global__ __launch_bounds__(512)
void k_reduce_weights(const unsigned* __restrict__ pairs,
                      const unsigned* __restrict__ base,
                      const int* __restrict__ numbers,
                      const float* __restrict__ ref_cn_table,
                      const float* __restrict__ r4r2,
                      __half* __restrict__ rec,
                      int n_atoms, int nb) {
    __shared__ unsigned hist[512];
    hist[threadIdx.x] = 0;
    __syncthreads();
    int b = blockIdx.x;
    unsigned start = base[b];
    unsigned end   = base[b + 1];
    for (unsigned k = start + threadIdx.x; k < end; k += 512) {
        unsigned p = pairs[k];
        atomicAdd(&hist[p >> 22], p & Q_MAX);
    }
    __syncthreads();
    int a = (b << 9) + threadIdx.x;
    if (a < n_atoms) {
        float c = (float)hist[threadIdx.x] * Q_INV;
        int Z = numbers[a];
        float w[5];
        float s = 0.0f;
#pragma unroll
        for (int r = 0; r < 5; ++r) {
            float rcn = ref_cn_table[Z * 5 + r];
            float d = rcn - c;
            float wv = (rcn >= 0.0f) ? expf(-WF_F * d * d) : 0.0f;
            w[r] = wv;
            s += wv;
        }
        float den = s + EPS_F;
        __half* rr = rec + (size_t)a * 8;
#pragma unroll
        for (int r = 0; r < 5; ++r) rr[r] = __float2half(w[r] / den);
        rr[5] = __float2half(r4r2[Z]);
        rr[6] = __float2half((float)Z);
        rr[7] = __float2half(0.0f);
    }
}

// ---------------- atomic fallback path ----------------
template<bool STASH>
__global__ __launch_bounds__(256)
void k_edges_cn_atomic(const float* __restrict__ dr_vec,
                       const int* __restrict__ idx_i,
                       const int* __restrict__ idx_j,
                       const float* __restrict__ rcovA,
                       unsigned* __restrict__ cn_u32,
                       float* __restrict__ dr_stash,
                       int n_edges) {
    int e = blockIdx.x * blockDim.x + threadIdx.x;
    if (e >= n_edges) return;
    float x = dr_vec[3 * e + 0];
    float y = dr_vec[3 * e + 1];
    float z = dr_vec[3 * e + 2];
    float dr = sqrtf(x * x + y * y + z * z) / BOHR_F;
    if (STASH) dr_stash[e] = dr;
    int i = idx_i[e];
    int j = idx_j[e];
    float m = edge_m(dr, rcovA[i] + rcovA[j]);
    unsigned q = (unsigned)(m * CN_SCALE + 0.5f);
    if (q) atomicAdd(&cn_u32[i], q);
}

__global__ __launch_bounds__(256)
void k_atom_weights_rec(const unsigned* __restrict__ cn_u32,
                        const int* __restrict__ numbers,
                        const float* __restrict__ ref_cn_table,
                        const float* __restrict__ r4r2,
                        __half* __restrict__ rec,
                        int n_atoms) {
    int a = blockIdx.x * blockDim.x + threadIdx.x;
    if (a >= n_atoms) return;
    float c = (float)cn_u32[a] * CN_INV;
    int Z = numbers[a];
    float w[5];
    float s = 0.0f;
#pragma unroll
    for (int r = 0; r < 5; ++r) {
        float rcn = ref_cn_table[Z * 5 + r];
        float d = rcn - c;
        float wv = (rcn >= 0.0f) ? expf(-WF_F * d * d) : 0.0f;
        w[r] = wv;
        s += wv;
    }
    float den = s + EPS_F;
    __half* rr = rec + (size_t)a * 8;
#pragma unroll
    for (int r = 0; r < 5; ++r) rr[r] = __float2half(w[r] / den);
    rr[5] = __float2half(r4r2[Z]);
    rr[6] = __float2half((float)Z);
    rr[7] = __float2half(0.0f);
}

// ---------------- energy (shared) ----------------
template<bool STASH>
__global__ __launch_bounds__(256)
void k_energy(const float* __restrict__ dr_vec,
              const float* __restrict__ dr_stash,
              const int* __restrict__ idx_i,
              const int* __restrict__ idx_j,
              const __half* __restrict__ rec,    // [N,8] halfs
              const __half* __restrict__ c6h,    // [95*95][32] halfs
              double* __restrict__ e_acc,
              int n_edges) {
    double local = 0.0;
    int nquad = (n_edges + 3) >> 2;
    int tid = blockIdx.x * blockDim.x + threadIdx.x;
    int stride = gridDim.x * blockDim.x;
    for (int qd = tid; qd < nquad; qd += stride) {
        int e0 = qd << 2;
        int ne = n_edges - e0;
        if (ne > 4) ne = 4;
        if (ne == 4) {
            int4 i4 = *reinterpret_cast<const int4*>(idx_i + e0);
            int4 j4 = *reinterpret_cast<const int4*>(idx_j + e0);
            int ia[4] = { i4.x, i4.y, i4.z, i4.w };
            int ja[4] = { j4.x, j4.y, j4.z, j4.w };
            float drq[4];
            if (STASH) {
                float4 d4 = *reinterpret_cast<const float4*>(dr_stash + e0);
                drq[0] = d4.x; drq[1] = d4.y; drq[2] = d4.z; drq[3] = d4.w;
            } else {
                float4 v0 = *reinterpret_cast<const float4*>(dr_vec + 3 * e0);
                float4 v1 = *reinterpret_cast<const float4*>(dr_vec + 3 * e0 + 4);
                float4 v2 = *reinterpret_cast<const float4*>(dr_vec + 3 * e0 + 8);
                drq[0] = sqrtf(v0.x*v0.x + v0.y*v0.y + v0.z*v0.z) / BOHR_F;
                drq[1] = sqrtf(v0.w*v0.w + v1.x*v1.x + v1.y*v1.y) / BOHR_F;
                drq[2] = sqrtf(v1.z*v1.z + v1.w*v1.w + v2.x*v2.x) / BOHR_F;
                drq[3] = sqrtf(v2.y*v2.y + v2.z*v2.z + v2.w*v2.w) / BOHR_F;
            }
            uint4 Ri[4], Rj[4];
#pragma unroll
            for (int k = 0; k < 4; ++k) {
                Ri[k] = *reinterpret_cast<const uint4*>(rec + (size_t)ia[k] * 8);
                Rj[k] = *reinterpret_cast<const uint4*>(rec + (size_t)ja[k] * 8);
            }
#pragma unroll
            for (int k = 0; k < 4; ++k) {
                float wi[5], wj[5], qi, qj, zif, zjf, dum;
                u2f2(Ri[k].x, wi[0], wi[1]);
                u2f2(Ri[k].y, wi[2], wi[3]);
                u2f2(Ri[k].z, wi[4], qi);
                u2f2(Ri[k].w, zif, dum);
                u2f2(Rj[k].x, wj[0], wj[1]);
                u2f2(Rj[k].y, wj[2], wj[3]);
                u2f2(Rj[k].z, wj[4], qj);
                u2f2(Rj[k].w, zjf, dum);
                int Zi = (int)zif;
                int Zj = (int)zjf;
                float qq = 3.0f * qi * qj;
                const uint4* cp = reinterpret_cast<const uint4*>(
                    c6h + ((size_t)Zj * NELEM + (size_t)Zi) * C6PADH);
                uint4 c0 = cp[0], c1 = cp[1], c2 = cp[2];
                unsigned c24 = reinterpret_cast<const unsigned*>(cp)[12];
                float ct[26];
                u2f2(c0.x, ct[0],  ct[1]);
                u2f2(c0.y, ct[2],  ct[3]);
                u2f2(c0.z, ct[4],  ct[5]);
                u2f2(c0.w, ct[6],  ct[7]);
                u2f2(c1.x, ct[8],  ct[9]);
                u2f2(c1.y, ct[10], ct[11]);
                u2f2(c1.z, ct[12], ct[13]);
                u2f2(c1.w, ct[14], ct[15]);
                u2f2(c2.x, ct[16], ct[17]);
                u2f2(c2.y, ct[18], ct[19]);
                u2f2(c2.z, ct[20], ct[21]);
                u2f2(c2.w, ct[22], ct[23]);
                u2f2(c24,  ct[24], ct[25]);
                float c6 = 0.0f;
#pragma unroll
                for (int a = 0; a < 5; ++a) {
#pragma unroll
                    for (int b = 0; b < 5; ++b) {
                        c6 += wj[a] * wi[b] * ct[a * 5 + b];
                    }
                }
                float dr = drq[k];
                float rr = A1_F * sqrtf(qq) + A2_F;
                float dr2 = dr * dr;
                float dr6 = dr2 * dr2 * dr2;
                float dr8 = dr6 * dr2;
                float rr2 = rr * rr;
                float rr6 = rr2 * rr2 * rr2;
                float rr8 = rr6 * rr2;
                float damped = -c6 * (S6_F / (dr6 + rr6) + S8_F * qq / (dr8 + rr8));
                local += (double)(smooth_cutoff(dr, 55.0f, 60.0f) * damped * 0.5f);
            }
        } else {
            for (int k = 0; k < ne; ++k) {
                int e = e0 + k;
                float dr;
                if (STASH) dr = dr_stash[e];
                else {
                    float x = dr_vec[3*e], y = dr_vec[3*e+1], z = dr_vec[3*e+2];
                    dr = sqrtf(x*x + y*y + z*z) / BOHR_F;
                }
                int i = idx_i[e], j = idx_j[e];
                const __half* pi = rec + (size_t)i * 8;
                const __half* pj = rec + (size_t)j * 8;
                int zi = (int)__half2float(pi[6]);
                int zj = (int)__half2float(pj[6]);
                float qq = 3.0f * __half2float(pi[5]) * __half2float(pj[5]);
                const __half* c6t = c6h + ((size_t)zj * NELEM + (size_t)zi) * C6PADH;
                float c6 = 0.0f;
                for (int a = 0; a < 5; ++a)
                    for (int bq = 0; bq < 5; ++bq)
                        c6 += __half2float(pj[a]) * __half2float(pi[bq])
                            * __half2float(c6t[a * 5 + bq]);
                float rr = A1_F * sqrtf(qq) + A2_F;
                float dr2 = dr * dr;
                float dr6 = dr2 * dr2 * dr2;
                float dr8 = dr6 * dr2;
                float rr2 = rr * rr;
                float rr6 = rr2 * rr2 * rr2;
                float rr8 = rr6 * rr2;
                float damped = -c6 * (S6_F / (dr6 + rr6) + S8_F * qq / (dr8 + rr8));
                local += (double)(smooth_cutoff(dr, 55.0f, 60.0f) * damped * 0.5f);
            }
        }
    }

    __shared__ double sdata[4];
    for (int off = 32; off > 0; off >>= 1)
        local += __shfl_down(local, off, 64);
    int lane = threadIdx.x & 63;
    int wid  = threadIdx.x >> 6;
    if (lane == 0) sdata[wid] = local;
    __syncthreads();
    if (threadIdx.x == 0) {
        double s = sdata[0] + sdata[1] + sdata[2] + sdata[3];
        atomicAdd(e_acc, s);
    }
}

__global__ void k_finalize(const double* __restrict__ e_acc,
                           float* __restrict__ out) {
    out[0] = (float)(e_acc[0] * HA_D);
}

static inline size_t a16(size_t x) { return (x + 15) & ~(size_t)15; }

extern "C" void kernel_launch(void* const* d_in, const int* in_sizes, int n_in,
                              void* d_out, int out_size, void* d_ws, size_t ws_size,
                              hipStream_t stream) {
    const float* dr_vec      = (const float*)d_in[0];
    const float* ref_cn_tab  = (const float*)d_in[1];
    const float* ref_c6_tab  = (const float*)d_in[2];
    const float* r4r2        = (const float*)d_in[3];
    const float* rcov        = (const float*)d_in[4];
    const int*   numbers     = (const int*)d_in[5];
    const int*   idx         = (const int*)d_in[6];

    int n_atoms = in_sizes[5];
    int n_edges = in_sizes[6] / 2;
    const int* idx_i = idx;
    const int* idx_j = idx + n_edges;

    const int BS = 256;
    int nb = (n_atoms + 511) >> 9;
    int c6tot = NELEM * NELEM * C6PADH;

    char* ws = (char*)d_ws;
    double* e_acc = (double*)ws;

    // common prefix: [e_acc 16][rec N*8 half][c6h][rcovA N]
    size_t off_rec = 16;
    size_t off_c6p = a16(off_rec + (size_t)n_atoms * 8 * 2);
    size_t off_rcA = a16(off_c6p + (size_t)c6tot * 2);
    size_t off_var = a16(off_rcA + (size_t)n_atoms * 4);

    // sort path: [packed E][pairs E][ghist nb*NBLK][totals nb][base nb+1][stash E]
    size_t off_packed = off_var;
    size_t off_pairs  = a16(off_packed + (size_t)n_edges * 4);
    size_t off_ghist  = a16(off_pairs + (size_t)n_edges * 4);
    size_t off_tot    = a16(off_ghist + (size_t)nb * NBLK * 4);
    size_t off_base   = a16(off_tot + (size_t)nb * 4);
    size_t off_stash  = a16(off_base + (size_t)(nb + 1) * 4);
    size_t need_sort       = off_stash;
    size_t need_sort_stash = off_stash + (size_t)n_edges * 4;

    // atomic path: [cn N][stash E]
    size_t off_cn   = off_var;
    size_t off_st_a = a16(off_cn + (size_t)n_atoms * 4);
    size_t need_atomic_stash = off_st_a + (size_t)n_edges * 4;

    int nquad  = (n_edges + 3) >> 2;
    int grid_q = (nquad + BS - 1) / BS;
    if (grid_q > 8192) grid_q = 8192;
    int grid_c6 = (c6tot + BS - 1) / BS;
    int grid_a  = (n_atoms + BS - 1) / BS;

    __half* rec   = (__half*)(ws + off_rec);
    __half* c6h   = (__half*)(ws + off_c6p);
    float*  rcovA = (float*)(ws + off_rcA);

    k_prep_c6<<<grid_c6, BS, 0, stream>>>(ref_c6_tab, c6h, c6tot);
    k_prep_rcov<<<grid_a, BS, 0, stream>>>(numbers, rcov, rcovA, n_atoms);

    if (nb <= 256 && ws_size >= need_sort) {
        bool stash = (ws_size >= need_sort_stash);
        unsigned* packed = (unsigned*)(ws + off_packed);
        unsigned* pairs  = (unsigned*)(ws + off_pairs);
        unsigned* ghist  = (unsigned*)(ws + off_ghist);
        unsigned* totals = (unsigned*)(ws + off_tot);
        unsigned* base   = (unsigned*)(ws + off_base);
        float* dr_stash  = stash ? (float*)(ws + off_stash) : nullptr;

        hipMemsetAsync(d_ws, 0, 16, stream);   // e_acc only

        if (stash)
            k_bin<true><<<NBLK, BSW, 0, stream>>>(dr_vec, idx_i, idx_j, rcovA,
                packed, ghist, dr_stash, n_edges, nb);
        else
            k_bin<false><<<NBLK, BSW, 0, stream>>>(dr_vec, idx_i, idx_j, rcovA,
                packed, ghist, nullptr, n_edges, nb);

        k_scan_bucket<<<nb, NBLK, 0, stream>>>(ghist, totals);
        k_scan_base<<<1, 256, 0, stream>>>(totals, base, nb);

        k_scatter<<<NBLK, BSW, 0, stream>>>(packed, idx_i, ghist, base, pairs,
                                            n_edges, nb);

        k_reduce_weights<<<nb, 512, 0, stream>>>(pairs, base, numbers,
            ref_cn_tab, r4r2, rec, n_atoms, nb);

        if (stash)
            k_energy<true><<<grid_q, BS, 0, stream>>>(dr_vec, dr_stash, idx_i,
                idx_j, rec, c6h, e_acc, n_edges);
        else
            k_energy<false><<<grid_q, BS, 0, stream>>>(dr_vec, nullptr, idx_i,
                idx_j, rec, c6h, e_acc, n_edges);
    } else {
        bool stash = (ws_size >= need_atomic_stash);
        unsigned* cn_u32 = (unsigned*)(ws + off_cn);
        float* dr_stash  = stash ? (float*)(ws + off_st_a) : nullptr;

        hipMemsetAsync(d_ws, 0, 16, stream);
        hipMemsetAsync(cn_u32, 0, (size_t)n_atoms * 4, stream);

        int grid_e = (n_edges + BS - 1) / BS;

        if (stash)
            k_edges_cn_atomic<true><<<grid_e, BS, 0, stream>>>(dr_vec, idx_i,
                idx_j, rcovA, cn_u32, dr_stash, n_edges);
        else
            k_edges_cn_atomic<false><<<grid_e, BS, 0, stream>>>(dr_vec, idx_i,
                idx_j, rcovA, cn_u32, nullptr, n_edges);

        k_atom_weights_rec<<<grid_a, BS, 0, stream>>>(cn_u32, numbers,
            ref_cn_tab, r4r2, rec, n_atoms);

        if (stash)
            k_energy<true><<<grid_q, BS, 0, stream>>>(dr_vec, dr_stash, idx_i,
                idx_j, rec, c6h, e_acc, n_edges);
        else
            k_energy<false><<<grid_q, BS, 0, stream>>>(dr_vec, nullptr, idx_i,
                idx_j, rec, c6h, e_acc, n_edges);
    }

    k_finalize<<<1, 1, 0, stream>>>(e_acc, (float*)d_out);
}